// Round 2
// baseline (2417.589 us; speedup 1.0000x reference)
//
#include <hip/hip_runtime.h>

// ---------------------------------------------------------------------------
// CTRL transformer forward: B=2 S=1024 D=1280 H=16 DH=80 DFF=8192 L=4
// fp32 inputs/outputs (per reference), bf16 MFMA GEMMs, fp32 residual stream.
// R1: split-K for the two EPI_RESID GEMMs (atomicAdd epilogue).
// R2: 2-phase double-buffered main loop in gemm_bt. Old loop: STAGE ->
//     syncthreads (vmcnt(0) drain = full load latency exposed) -> MFMA ->
//     syncthreads. New loop: prefetch next tile, compute current, ONE
//     barrier per iter; the vmcnt(0) drain lands after the compute phase
//     has covered the HBM/L2 latency. (Guide T3 minimum-2-phase recipe.)
// ---------------------------------------------------------------------------

typedef unsigned short ushort_t;
typedef __attribute__((ext_vector_type(8))) __bf16 bf16x8;
typedef __attribute__((ext_vector_type(4))) float f32x4;

typedef const __attribute__((address_space(1))) unsigned int gu32;
typedef __attribute__((address_space(3))) unsigned int lu32;

#define DEV __device__ __forceinline__

DEV float bf2f(ushort_t h) { return __uint_as_float(((unsigned)h) << 16); }
DEV ushort_t f2bf(float f) {
    unsigned u = __float_as_uint(f);
    unsigned r = (u + 0x7fffu + ((u >> 16) & 1u)) >> 16;   // RNE
    return (ushort_t)r;
}

DEV void async16(const void* g, void* l) {
    // global -> LDS direct DMA, 16B/lane, LDS dst = wave-uniform base + lane*16
    __builtin_amdgcn_global_load_lds((gu32*)g, (lu32*)l, 16, 0, 0);
}

// ---------------------------------------------------------------------------
// Embedding * sqrt(D) + sinusoidal PE  ->  x (fp32 [2048][1280])
// ---------------------------------------------------------------------------
__global__ __launch_bounds__(256) void embed_k(const int* __restrict__ ids,
                                               const float* __restrict__ emb,
                                               float* __restrict__ x) {
    __shared__ int flag64;
    const int r = blockIdx.x, t = threadIdx.x;
    if (t == 0) {
        // int64 detection: if ids are int64, every odd 32-bit word is 0.
        int z = 0;
        for (int i = 1; i < 256; i += 2) z |= ids[i];
        flag64 = (z == 0);
    }
    __syncthreads();
    const long id = flag64 ? (long)((const long long*)ids)[r] : (long)ids[r];
    const float* er = emb + (size_t)id * 1280;
    const float pos = (float)(r & 1023);
    #pragma unroll
    for (int i = 0; i < 5; i++) {
        const int c = t + i * 256;
        float pe;
        if (c < 640) {
            float w = expf(-(float)c * 0.0143911568312128f);   // 10000^(-c/640)
            pe = sinf(pos * w);
        } else {
            float w = expf(-(float)(c - 640) * 0.0143911568312128f);
            pe = cosf(pos * w);
        }
        x[(size_t)r * 1280 + c] = er[c] * 35.77708763999664f + pe;
    }
}

// ---------------------------------------------------------------------------
// LayerNorm: fp32 src row -> bf16 (nbuf) or fp32 (d_out) row
// ---------------------------------------------------------------------------
template <typename OUT>
__global__ __launch_bounds__(256) void layernorm_k(const float* __restrict__ x,
                                                   const float* __restrict__ gw,
                                                   const float* __restrict__ bw,
                                                   OUT* __restrict__ out) {
    __shared__ float red[8];
    const int row = blockIdx.x, t = threadIdx.x;
    const float* xr = x + (size_t)row * 1280;
    float v[5], s = 0.f, ss = 0.f;
    #pragma unroll
    for (int i = 0; i < 5; i++) {
        v[i] = xr[t + i * 256];
        s += v[i];
        ss += v[i] * v[i];
    }
    #pragma unroll
    for (int o = 32; o; o >>= 1) {
        s += __shfl_xor(s, o, 64);
        ss += __shfl_xor(ss, o, 64);
    }
    if ((t & 63) == 0) { red[t >> 6] = s; red[4 + (t >> 6)] = ss; }
    __syncthreads();
    s = red[0] + red[1] + red[2] + red[3];
    ss = red[4] + red[5] + red[6] + red[7];
    const float mean = s * (1.f / 1280.f);
    const float var = ss * (1.f / 1280.f) - mean * mean;
    const float rs = rsqrtf(var + 1e-6f);
    #pragma unroll
    for (int i = 0; i < 5; i++) {
        const int c = t + i * 256;
        const float o = (v[i] - mean) * rs * gw[c] + bw[c];
        if constexpr (sizeof(OUT) == 2) out[(size_t)row * 1280 + c] = f2bf(o);
        else                            out[(size_t)row * 1280 + c] = o;
    }
}

// ---------------------------------------------------------------------------
// fp32 -> bf16 transpose: src fp32 [R][C] -> dst bf16 [C][R], 64x64 tiles
// ---------------------------------------------------------------------------
__global__ __launch_bounds__(256) void convtrans_k(const float* __restrict__ src,
                                                   ushort_t* __restrict__ dst,
                                                   int R, int C) {
    __shared__ float tile[64][65];
    const int bx = blockIdx.x * 64;   // C
    const int by = blockIdx.y * 64;   // R
    const int c = threadIdx.x & 63;
    const int r0 = threadIdx.x >> 6;  // 0..3
    #pragma unroll
    for (int r = r0; r < 64; r += 4)
        tile[r][c] = src[(size_t)(by + r) * C + bx + c];
    __syncthreads();
    #pragma unroll
    for (int j = r0; j < 64; j += 4)
        dst[(size_t)(bx + j) * R + by + c] = f2bf(tile[c][j]);
}

// ---------------------------------------------------------------------------
// Row softmax: fp32 scores [rows][1024] -> bf16 P [rows][1024]
// ---------------------------------------------------------------------------
__global__ __launch_bounds__(256) void softmax_k(const float* __restrict__ S,
                                                 ushort_t* __restrict__ P) {
    __shared__ float red[4];
    const size_t row = blockIdx.x;
    const int t = threadIdx.x;
    const float* sr = S + row * 1024;
    float v[4], m = -1e30f;
    #pragma unroll
    for (int i = 0; i < 4; i++) {
        v[i] = sr[t + i * 256];
        m = fmaxf(m, v[i]);
    }
    #pragma unroll
    for (int o = 32; o; o >>= 1) m = fmaxf(m, __shfl_xor(m, o, 64));
    if ((t & 63) == 0) red[t >> 6] = m;
    __syncthreads();
    m = fmaxf(fmaxf(red[0], red[1]), fmaxf(red[2], red[3]));
    float s = 0.f;
    #pragma unroll
    for (int i = 0; i < 4; i++) {
        v[i] = __expf(v[i] - m);
        s += v[i];
    }
    #pragma unroll
    for (int o = 32; o; o >>= 1) s += __shfl_xor(s, o, 64);
    __syncthreads();
    if ((t & 63) == 0) red[t >> 6] = s;
    __syncthreads();
    s = red[0] + red[1] + red[2] + red[3];
    const float inv = 1.f / s;
    #pragma unroll
    for (int i = 0; i < 4; i++)
        P[row * 1024 + t + i * 256] = f2bf(v[i] * inv);
}

// ---------------------------------------------------------------------------
// Zero filler for q/k/vT pad buffers (contiguous, 16B per thread)
// ---------------------------------------------------------------------------
__global__ void zero_k(float4* __restrict__ p) {
    p[(size_t)blockIdx.x * 256 + threadIdx.x] = make_float4(0.f, 0.f, 0.f, 0.f);
}

// ---------------------------------------------------------------------------
// gemm_bt compute helper: one 32-deep K-step of 4x4 16x16 fragments
// ---------------------------------------------------------------------------
DEV void gemm_compute(const ushort_t* as_, const ushort_t* bs_,
                      int wm, int wn, int l16, int quad, f32x4 (&acc)[4][4]) {
    bf16x8 af[4], bfv[4];
    #pragma unroll
    for (int i = 0; i < 4; i++)
        af[i] = *(const bf16x8*)&as_[(wm * 64 + i * 16 + l16) * 32 + quad * 8];
    #pragma unroll
    for (int j = 0; j < 4; j++)
        bfv[j] = *(const bf16x8*)&bs_[(wn * 64 + j * 16 + l16) * 32 + quad * 8];
    #pragma unroll
    for (int i = 0; i < 4; i++)
        #pragma unroll
        for (int j = 0; j < 4; j++)
            acc[i][j] = __builtin_amdgcn_mfma_f32_16x16x32_bf16(af[i], bfv[j], acc[i][j], 0, 0, 0);
}

// ---------------------------------------------------------------------------
// m97-style GEMM, 2-phase double-buffered: C[M][N] = A[M][K] @ Bt[N][K]^T
// 128x128 tile, BK=32, 256 thr (4 waves, 2x2 of 64x64), mfma 16x16x32 bf16.
// EPI_RESID: blockIdx.z = K-split index (gridDim.z splits); epilogue
//            atomicAdd into fp32 residual; bias added by split 0 only.
// ---------------------------------------------------------------------------
enum { EPI_QKV = 0, EPI_RELU = 1, EPI_RESID = 2, EPI_SC = 3, EPI_CTX = 4 };

template <int EPI>
__global__ __launch_bounds__(256, 2) void gemm_bt(
    const ushort_t* __restrict__ A, const ushort_t* __restrict__ Bt,
    const float* __restrict__ bias, const float* __restrict__ bias2,
    const float* __restrict__ bias3, float* __restrict__ outF,
    ushort_t* __restrict__ outB, ushort_t* __restrict__ outB2,
    ushort_t* __restrict__ outB3,
    int K, int lda, int ldb, int nAlloc, int ldc,
    long aStr, long bStr, long cStr, int g0, float scaleP) {
    // double-buffered: [2][128 rows][32 bf16] = 2 x 8 KB each for A and B
    __shared__ __align__(16) ushort_t As[2][128 * 32];
    __shared__ __align__(16) ushort_t Bs[2][128 * 32];

    const int t = threadIdx.x;
    const int lane = t & 63, wave = t >> 6;
    const int wm = wave >> 1, wn = wave & 1;
    const int l16 = lane & 15, quad = lane >> 4;
    const int tileM = blockIdx.y * 128, tileN = blockIdx.x * 128;
    const long z = blockIdx.z;

    const ushort_t* Ab = A + z * aStr;
    const ushort_t* Bb = Bt + z * bStr;

    // K-split (EPI_RESID only): block z covers [kBeg, kEnd)
    int kBeg = 0, kEnd = K;
    if (EPI == EPI_RESID) {
        const int kc = K / (int)gridDim.z;
        kBeg = (int)z * kc;
        kEnd = kBeg + kc;
    }
    const int nt = (kEnd - kBeg) >> 5;   // K-steps of 32

    // staging map: thread t covers row rowS (chunk0) and rowS+64 (chunk1),
    // 16B at byte kb of the 64B (BK=32 bf16) row slice
    const int rowS = t >> 2;          // 0..63
    const int kb = (t & 3) * 16;      // 0/16/32/48

    const int rb0 = min(tileN + rowS, nAlloc - 1);
    const int rb1 = min(tileN + rowS + 64, nAlloc - 1);

    const char* apc0 = (const char*)Ab + ((size_t)(tileM + rowS) * lda + kBeg) * 2 + kb;
    const char* apc1 = apc0 + (size_t)64 * lda * 2;
    const char* bpc0 = (const char*)Bb + ((size_t)rb0 * ldb + kBeg) * 2 + kb;
    const char* bpc1 = (const char*)Bb + ((size_t)rb1 * ldb + kBeg) * 2 + kb;

    // per-wave LDS staging bases (buffer 0); buffer 1 = +8192 bytes
    char* lA = (char*)As + wave * 1024;
    char* lB = (char*)Bs + wave * 1024;

    f32x4 acc[4][4] = {};

    // prologue: stage tile 0 into buffer 0
    async16(apc0, lA);
    async16(apc1, lA + 4096);
    async16(bpc0, lB);
    async16(bpc1, lB + 4096);
    apc0 += 64; apc1 += 64; bpc0 += 64; bpc1 += 64;
    __syncthreads();   // vmcnt(0) drain: buffer 0 ready

    int bo_ = 0;   // byte offset of current buffer (0 or 8192)
    for (int tt = 0; tt < nt - 1; ++tt) {
        // prefetch next K-step into the other buffer (issue-early)
        const int po = bo_ ^ 8192;
        async16(apc0, lA + po);
        async16(apc1, lA + po + 4096);
        async16(bpc0, lB + po);
        async16(bpc1, lB + po + 4096);
        apc0 += 64; apc1 += 64; bpc0 += 64; bpc1 += 64;
        // compute current buffer: loads fly under ds_read + 16 MFMA
        gemm_compute((const ushort_t*)((const char*)As + bo_),
                     (const ushort_t*)((const char*)Bs + bo_),
                     wm, wn, l16, quad, acc);
        __syncthreads();   // single barrier/iter; drains prefetch after compute
        bo_ = po;
    }
    // final K-step: no prefetch
    gemm_compute((const ushort_t*)((const char*)As + bo_),
                 (const ushort_t*)((const char*)Bs + bo_),
                 wm, wn, l16, quad, acc);

    // epilogue: within 16x16 tile, row = quad*4+g, col = l16
    #pragma unroll
    for (int i = 0; i < 4; i++) {
        const int r0 = tileM + wm * 64 + i * 16 + quad * 4;
        #pragma unroll
        for (int j = 0; j < 4; j++) {
            const int c = tileN + wn * 64 + j * 16 + l16;
            float bv = 0.f;
            if (EPI == EPI_QKV) {
                const float* bp = bias;
                int cc = c;
                if (c >= 2560) { cc = c - 2560; bp = bias3; }
                else if (c >= 1280) { cc = c - 1280; bp = bias2; }
                bv = bp[cc];
            } else if (EPI == EPI_RELU) {
                bv = bias[c];
            } else if (EPI == EPI_RESID) {
                bv = (z == 0) ? bias[c] : 0.f;
            }
            #pragma unroll
            for (int g = 0; g < 4; g++) {
                const int r = r0 + g;
                const float v = acc[i][j][g] + bv;
                if (EPI == EPI_QKV) {
                    int cc = c;
                    ushort_t* ob = outB;
                    bool isV = false;
                    if (c >= 2560) { cc = c - 2560; ob = outB3; isV = true; }
                    else if (c >= 1280) { cc = c - 1280; ob = outB2; }
                    const int b = r >> 10, s = r & 1023;
                    const int h = cc / 80, d = cc - h * 80;
                    if (isV) ob[((size_t)((b * 16 + h) * 96 + d)) * 1024 + s] = f2bf(v);
                    else     ob[((size_t)((b * 16 + h) * 1024 + s)) * 96 + d] = f2bf(v);
                } else if (EPI == EPI_RELU) {
                    outB[(size_t)r * ldc + c] = f2bf(fmaxf(v, 0.f));
                } else if (EPI == EPI_RESID) {
                    atomicAdd(outF + (size_t)r * ldc + c, v);
                } else if (EPI == EPI_SC) {
                    float sv = acc[i][j][g] * scaleP;
                    if (c > r) sv -= 10000.f;
                    outF[z * cStr + (size_t)r * ldc + c] = sv;
                } else {  // EPI_CTX
                    if (c < 80) {
                        const int gg = g0 + (int)z;
                        const int b = gg >> 4, h = gg & 15;
                        outB[((size_t)(b * 1024 + r)) * 1280 + h * 80 + c] = f2bf(acc[i][j][g]);
                    }
                }
            }
        }
    }
}

// ---------------------------------------------------------------------------
// Host orchestration
// ---------------------------------------------------------------------------
extern "C" void kernel_launch(void* const* d_in, const int* in_sizes, int n_in,
                              void* d_out, int out_size, void* d_ws, size_t ws_size,
                              hipStream_t stream) {
    const int* ids = (const int*)d_in[0];
    const float* emb = (const float*)d_in[1];
    const float* Wq = (const float*)d_in[2];
    const float* Wk = (const float*)d_in[3];
    const float* Wv = (const float*)d_in[4];
    const float* Wo = (const float*)d_in[5];
    const float* bq = (const float*)d_in[6];
    const float* bk = (const float*)d_in[7];
    const float* bv = (const float*)d_in[8];
    const float* bo = (const float*)d_in[9];
    const float* W1 = (const float*)d_in[10];
    const float* b1 = (const float*)d_in[11];
    const float* W2 = (const float*)d_in[12];
    const float* b2 = (const float*)d_in[13];
    const float* ln1g = (const float*)d_in[14];
    const float* ln1b = (const float*)d_in[15];
    const float* ln2g = (const float*)d_in[16];
    const float* ln2b = (const float*)d_in[17];
    const float* lnfg = (const float*)d_in[18];
    const float* lnfb = (const float*)d_in[19];
    (void)in_sizes; (void)n_in; (void)out_size; (void)ws_size;

    char* p = (char*)d_ws;
    float* xf = (float*)p;          p += (size_t)2048 * 1280 * 4;     // residual (10.49 MB)
    ushort_t* nbuf = (ushort_t*)p;  p += (size_t)2048 * 1280 * 2;     // LN out bf16 (5.24 MB)
    ushort_t* qp = (ushort_t*)p;    p += (size_t)32 * 1024 * 96 * 2;  // q [bh][s][96] (6.29 MB)
    ushort_t* kp = (ushort_t*)p;    p += (size_t)32 * 1024 * 96 * 2;  // k [bh][s][96]
    ushort_t* vT = (ushort_t*)p;    p += (size_t)32 * 96 * 1024 * 2;  // v^T [bh][96][1024]
    ushort_t* ctx = (ushort_t*)p;   p += (size_t)2048 * 1280 * 2;     // attn out (5.24 MB)
    ushort_t* h1 = (ushort_t*)p;    p += (size_t)2048 * 8192 * 2;     // FFN hidden (33.55 MB)
    ushort_t* WT = (ushort_t*)p;    p += (size_t)8192 * 1280 * 2;     // bf16 W^T (20.97 MB)
    // attention score/prob buffers OVERLAP h1 (dead during attention) + WT:
    // Sb = CH*4 MB fp32, Pb = CH*2 MB bf16, CH=8 -> 32 MB + 16 MB
    float* Sb = (float*)h1;
    ushort_t* Pb = WT;
    const int CH = 8;

    const float scaleP = 0.11180339887498948f;   // 1/sqrt(80)

    embed_k<<<2048, 256, 0, stream>>>(ids, emb, xf);
    zero_k<<<4608, 256, 0, stream>>>((float4*)qp);   // qp,kp,vT = 18.87 MB contiguous

    for (int l = 0; l < 4; l++) {
        const float* Wq_l = Wq + (size_t)l * 1638400;
        const float* Wk_l = Wk + (size_t)l * 1638400;
        const float* Wv_l = Wv + (size_t)l * 1638400;
        const float* Wo_l = Wo + (size_t)l * 1638400;
        const float* W1_l = W1 + (size_t)l * 10485760;
        const float* W2_l = W2 + (size_t)l * 10485760;

        layernorm_k<ushort_t><<<2048, 256, 0, stream>>>(xf, ln1g + l * 1280, ln1b + l * 1280, nbuf);

        // WT rows 0..1279 = Wq^T, 1280..2559 = Wk^T, 2560..3839 = Wv^T
        convtrans_k<<<dim3(20, 20), 256, 0, stream>>>(Wq_l, WT, 1280, 1280);
        convtrans_k<<<dim3(20, 20), 256, 0, stream>>>(Wk_l, WT + (size_t)1280 * 1280, 1280, 1280);
        convtrans_k<<<dim3(20, 20), 256, 0, stream>>>(Wv_l, WT + (size_t)2560 * 1280, 1280, 1280);
        gemm_bt<EPI_QKV><<<dim3(30, 16, 1), 256, 0, stream>>>(
            nbuf, WT, bq + l * 1280, bk + l * 1280, bv + l * 1280,
            nullptr, qp, kp, vT, 1280, 1280, 1280, 3840, 0, 0, 0, 0, 0, 0.f);

        for (int c0 = 0; c0 < 32; c0 += CH) {
            gemm_bt<EPI_SC><<<dim3(8, 8, CH), 256, 0, stream>>>(
                qp + (size_t)c0 * 98304, kp + (size_t)c0 * 98304, nullptr, nullptr, nullptr,
                Sb, nullptr, nullptr, nullptr,
                96, 96, 96, 1024, 1024, 98304, 98304, 1048576, 0, scaleP);
            softmax_k<<<CH * 1024, 256, 0, stream>>>(Sb, Pb);
            gemm_bt<EPI_CTX><<<dim3(1, 8, CH), 256, 0, stream>>>(
                Pb, vT + (size_t)c0 * 98304, nullptr, nullptr, nullptr,
                nullptr, ctx, nullptr, nullptr,
                1024, 1024, 1024, 96, 0, 1048576, 98304, 0, c0, 0.f);
        }

        convtrans_k<<<dim3(20, 20), 256, 0, stream>>>(Wo_l, WT, 1280, 1280);
        // Wo projection: split-K x4 -> 640 blocks
        gemm_bt<EPI_RESID><<<dim3(10, 16, 4), 256, 0, stream>>>(
            ctx, WT, bo + l * 1280, nullptr, nullptr,
            xf, nullptr, nullptr, nullptr,
            1280, 1280, 1280, 1280, 1280, 0, 0, 0, 0, 0.f);

        layernorm_k<ushort_t><<<2048, 256, 0, stream>>>(xf, ln2g + l * 1280, ln2b + l * 1280, nbuf);

        convtrans_k<<<dim3(128, 20), 256, 0, stream>>>(W1_l, WT, 1280, 8192);
        gemm_bt<EPI_RELU><<<dim3(64, 16, 1), 256, 0, stream>>>(
            nbuf, WT, b1 + l * 8192, nullptr, nullptr,
            nullptr, h1, nullptr, nullptr,
            1280, 1280, 1280, 8192, 8192, 0, 0, 0, 0, 0.f);

        convtrans_k<<<dim3(20, 128), 256, 0, stream>>>(W2_l, WT, 8192, 1280);
        // FFN2: split-K x8 -> 1280 blocks, 32 K-iters per block
        gemm_bt<EPI_RESID><<<dim3(10, 16, 8), 256, 0, stream>>>(
            h1, WT, b2 + l * 1280, nullptr, nullptr,
            xf, nullptr, nullptr, nullptr,
            8192, 8192, 8192, 1280, 1280, 0, 0, 0, 0, 0.f);
    }

    layernorm_k<float><<<2048, 256, 0, stream>>>(xf, lnfg, lnfb, (float*)d_out);
}

// Round 4
// 2385.484 us; speedup vs baseline: 1.0135x; 1.0135x over previous
//
#include <hip/hip_runtime.h>

// ---------------------------------------------------------------------------
// CTRL transformer forward: B=2 S=1024 D=1280 H=16 DH=80 DFF=8192 L=4
// fp32 inputs/outputs (per reference), bf16 MFMA GEMMs, fp32 residual stream.
// R1: split-K for the two EPI_RESID GEMMs (atomicAdd epilogue).
// R2: 2-phase double-buffered main loop in gemm_bt (kept; neutral alone).
// R3: XCD-aware bijective block swizzle (T1/m204) in gemm_bt. Diagnosis:
//     FFN2 is L2-miss-traffic bound (FETCH 254 MB vs 55 MB unique; round-
//     robin block->XCD scatter makes every 4 MB XCD-L2 touch the whole
//     working set). Chunked y-fastest remap gives each XCD a contiguous
//     tile region: FFN2 -> one K-split slice/XCD (6.6 MB), FFN1 -> 8
//     N-columns/XCD (2.6 MB B-panel), SC/CTX -> one head/XCD.
// R4: resubmit of R3 (container infra failure; kernel unchanged).
// ---------------------------------------------------------------------------

typedef unsigned short ushort_t;
typedef __attribute__((ext_vector_type(8))) __bf16 bf16x8;
typedef __attribute__((ext_vector_type(4))) float f32x4;

typedef const __attribute__((address_space(1))) unsigned int gu32;
typedef __attribute__((address_space(3))) unsigned int lu32;

#define DEV __device__ __forceinline__

DEV float bf2f(ushort_t h) { return __uint_as_float(((unsigned)h) << 16); }
DEV ushort_t f2bf(float f) {
    unsigned u = __float_as_uint(f);
    unsigned r = (u + 0x7fffu + ((u >> 16) & 1u)) >> 16;   // RNE
    return (ushort_t)r;
}

DEV void async16(const void* g, void* l) {
    // global -> LDS direct DMA, 16B/lane, LDS dst = wave-uniform base + lane*16
    __builtin_amdgcn_global_load_lds((gu32*)g, (lu32*)l, 16, 0, 0);
}

// ---------------------------------------------------------------------------
// Embedding * sqrt(D) + sinusoidal PE  ->  x (fp32 [2048][1280])
// ---------------------------------------------------------------------------
__global__ __launch_bounds__(256) void embed_k(const int* __restrict__ ids,
                                               const float* __restrict__ emb,
                                               float* __restrict__ x) {
    __shared__ int flag64;
    const int r = blockIdx.x, t = threadIdx.x;
    if (t == 0) {
        // int64 detection: if ids are int64, every odd 32-bit word is 0.
        int z = 0;
        for (int i = 1; i < 256; i += 2) z |= ids[i];
        flag64 = (z == 0);
    }
    __syncthreads();
    const long id = flag64 ? (long)((const long long*)ids)[r] : (long)ids[r];
    const float* er = emb + (size_t)id * 1280;
    const float pos = (float)(r & 1023);
    #pragma unroll
    for (int i = 0; i < 5; i++) {
        const int c = t + i * 256;
        float pe;
        if (c < 640) {
            float w = expf(-(float)c * 0.0143911568312128f);   // 10000^(-c/640)
            pe = sinf(pos * w);
        } else {
            float w = expf(-(float)(c - 640) * 0.0143911568312128f);
            pe = cosf(pos * w);
        }
        x[(size_t)r * 1280 + c] = er[c] * 35.77708763999664f + pe;
    }
}

// ---------------------------------------------------------------------------
// LayerNorm: fp32 src row -> bf16 (nbuf) or fp32 (d_out) row
// ---------------------------------------------------------------------------
template <typename OUT>
__global__ __launch_bounds__(256) void layernorm_k(const float* __restrict__ x,
                                                   const float* __restrict__ gw,
                                                   const float* __restrict__ bw,
                                                   OUT* __restrict__ out) {
    __shared__ float red[8];
    const int row = blockIdx.x, t = threadIdx.x;
    const float* xr = x + (size_t)row * 1280;
    float v[5], s = 0.f, ss = 0.f;
    #pragma unroll
    for (int i = 0; i < 5; i++) {
        v[i] = xr[t + i * 256];
        s += v[i];
        ss += v[i] * v[i];
    }
    #pragma unroll
    for (int o = 32; o; o >>= 1) {
        s += __shfl_xor(s, o, 64);
        ss += __shfl_xor(ss, o, 64);
    }
    if ((t & 63) == 0) { red[t >> 6] = s; red[4 + (t >> 6)] = ss; }
    __syncthreads();
    s = red[0] + red[1] + red[2] + red[3];
    ss = red[4] + red[5] + red[6] + red[7];
    const float mean = s * (1.f / 1280.f);
    const float var = ss * (1.f / 1280.f) - mean * mean;
    const float rs = rsqrtf(var + 1e-6f);
    #pragma unroll
    for (int i = 0; i < 5; i++) {
        const int c = t + i * 256;
        const float o = (v[i] - mean) * rs * gw[c] + bw[c];
        if constexpr (sizeof(OUT) == 2) out[(size_t)row * 1280 + c] = f2bf(o);
        else                            out[(size_t)row * 1280 + c] = o;
    }
}

// ---------------------------------------------------------------------------
// fp32 -> bf16 transpose: src fp32 [R][C] -> dst bf16 [C][R], 64x64 tiles
// ---------------------------------------------------------------------------
__global__ __launch_bounds__(256) void convtrans_k(const float* __restrict__ src,
                                                   ushort_t* __restrict__ dst,
                                                   int R, int C) {
    __shared__ float tile[64][65];
    const int bx = blockIdx.x * 64;   // C
    const int by = blockIdx.y * 64;   // R
    const int c = threadIdx.x & 63;
    const int r0 = threadIdx.x >> 6;  // 0..3
    #pragma unroll
    for (int r = r0; r < 64; r += 4)
        tile[r][c] = src[(size_t)(by + r) * C + bx + c];
    __syncthreads();
    #pragma unroll
    for (int j = r0; j < 64; j += 4)
        dst[(size_t)(bx + j) * R + by + c] = f2bf(tile[c][j]);
}

// ---------------------------------------------------------------------------
// Row softmax: fp32 scores [rows][1024] -> bf16 P [rows][1024]
// ---------------------------------------------------------------------------
__global__ __launch_bounds__(256) void softmax_k(const float* __restrict__ S,
                                                 ushort_t* __restrict__ P) {
    __shared__ float red[4];
    const size_t row = blockIdx.x;
    const int t = threadIdx.x;
    const float* sr = S + row * 1024;
    float v[4], m = -1e30f;
    #pragma unroll
    for (int i = 0; i < 4; i++) {
        v[i] = sr[t + i * 256];
        m = fmaxf(m, v[i]);
    }
    #pragma unroll
    for (int o = 32; o; o >>= 1) m = fmaxf(m, __shfl_xor(m, o, 64));
    if ((t & 63) == 0) red[t >> 6] = m;
    __syncthreads();
    m = fmaxf(fmaxf(red[0], red[1]), fmaxf(red[2], red[3]));
    float s = 0.f;
    #pragma unroll
    for (int i = 0; i < 4; i++) {
        v[i] = __expf(v[i] - m);
        s += v[i];
    }
    #pragma unroll
    for (int o = 32; o; o >>= 1) s += __shfl_xor(s, o, 64);
    __syncthreads();
    if ((t & 63) == 0) red[t >> 6] = s;
    __syncthreads();
    s = red[0] + red[1] + red[2] + red[3];
    const float inv = 1.f / s;
    #pragma unroll
    for (int i = 0; i < 4; i++)
        P[row * 1024 + t + i * 256] = f2bf(v[i] * inv);
}

// ---------------------------------------------------------------------------
// Zero filler for q/k/vT pad buffers (contiguous, 16B per thread)
// ---------------------------------------------------------------------------
__global__ void zero_k(float4* __restrict__ p) {
    p[(size_t)blockIdx.x * 256 + threadIdx.x] = make_float4(0.f, 0.f, 0.f, 0.f);
}

// ---------------------------------------------------------------------------
// gemm_bt compute helper: one 32-deep K-step of 4x4 16x16 fragments
// ---------------------------------------------------------------------------
DEV void gemm_compute(const ushort_t* as_, const ushort_t* bs_,
                      int wm, int wn, int l16, int quad, f32x4 (&acc)[4][4]) {
    bf16x8 af[4], bfv[4];
    #pragma unroll
    for (int i = 0; i < 4; i++)
        af[i] = *(const bf16x8*)&as_[(wm * 64 + i * 16 + l16) * 32 + quad * 8];
    #pragma unroll
    for (int j = 0; j < 4; j++)
        bfv[j] = *(const bf16x8*)&bs_[(wn * 64 + j * 16 + l16) * 32 + quad * 8];
    #pragma unroll
    for (int i = 0; i < 4; i++)
        #pragma unroll
        for (int j = 0; j < 4; j++)
            acc[i][j] = __builtin_amdgcn_mfma_f32_16x16x32_bf16(af[i], bfv[j], acc[i][j], 0, 0, 0);
}

// ---------------------------------------------------------------------------
// m97-style GEMM, 2-phase double-buffered, XCD-chunked: C = A @ Bt^T
// 128x128 tile, BK=32, 256 thr (4 waves, 2x2 of 64x64), mfma 16x16x32 bf16.
// EPI_RESID: tz = K-split index (gridDim.z splits); epilogue atomicAdd into
//            fp32 residual; bias added by split 0 only.
// ---------------------------------------------------------------------------
enum { EPI_QKV = 0, EPI_RELU = 1, EPI_RESID = 2, EPI_SC = 3, EPI_CTX = 4 };

template <int EPI>
__global__ __launch_bounds__(256, 2) void gemm_bt(
    const ushort_t* __restrict__ A, const ushort_t* __restrict__ Bt,
    const float* __restrict__ bias, const float* __restrict__ bias2,
    const float* __restrict__ bias3, float* __restrict__ outF,
    ushort_t* __restrict__ outB, ushort_t* __restrict__ outB2,
    ushort_t* __restrict__ outB3,
    int K, int lda, int ldb, int nAlloc, int ldc,
    long aStr, long bStr, long cStr, int g0, float scaleP) {
    // double-buffered: [2][128 rows][32 bf16] = 2 x 8 KB each for A and B
    __shared__ __align__(16) ushort_t As[2][128 * 32];
    __shared__ __align__(16) ushort_t Bs[2][128 * 32];

    const int t = threadIdx.x;
    const int lane = t & 63, wave = t >> 6;
    const int wm = wave >> 1, wn = wave & 1;
    const int l16 = lane & 15, quad = lane >> 4;

    // --- T1/m204 XCD-aware bijective chunking -----------------------------
    // HW dispatch id (x-fastest) round-robins XCDs: xcd ~ orig % 8. Remap so
    // each XCD covers a contiguous y-fastest chunk of (y, x, z) tile space.
    const int gx = gridDim.x, gy = gridDim.y;
    const int nwg = gx * gy * (int)gridDim.z;
    const int orig = (int)blockIdx.x + gx * ((int)blockIdx.y + gy * (int)blockIdx.z);
    const int q8 = nwg >> 3, r8 = nwg & 7;
    const int xcd = orig & 7, slot = orig >> 3;
    const int lin = slot + ((xcd < r8) ? xcd * (q8 + 1) : r8 + xcd * q8);
    const int ty = lin % gy;
    const int txz = lin / gy;
    const int tx = txz % gx;
    const int tz = txz / gx;
    // ----------------------------------------------------------------------

    const int tileM = ty * 128, tileN = tx * 128;
    const long z = tz;

    const ushort_t* Ab = A + z * aStr;
    const ushort_t* Bb = Bt + z * bStr;

    // K-split (EPI_RESID only): split z covers [kBeg, kEnd)
    int kBeg = 0, kEnd = K;
    if (EPI == EPI_RESID) {
        const int kc = K / (int)gridDim.z;
        kBeg = (int)z * kc;
        kEnd = kBeg + kc;
    }
    const int nt = (kEnd - kBeg) >> 5;   // K-steps of 32

    // staging map: thread t covers row rowS (chunk0) and rowS+64 (chunk1),
    // 16B at byte kb of the 64B (BK=32 bf16) row slice
    const int rowS = t >> 2;          // 0..63
    const int kb = (t & 3) * 16;      // 0/16/32/48

    const int rb0 = min(tileN + rowS, nAlloc - 1);
    const int rb1 = min(tileN + rowS + 64, nAlloc - 1);

    const char* apc0 = (const char*)Ab + ((size_t)(tileM + rowS) * lda + kBeg) * 2 + kb;
    const char* apc1 = apc0 + (size_t)64 * lda * 2;
    const char* bpc0 = (const char*)Bb + ((size_t)rb0 * ldb + kBeg) * 2 + kb;
    const char* bpc1 = (const char*)Bb + ((size_t)rb1 * ldb + kBeg) * 2 + kb;

    // per-wave LDS staging bases (buffer 0); buffer 1 = +8192 bytes
    char* lA = (char*)As + wave * 1024;
    char* lB = (char*)Bs + wave * 1024;

    f32x4 acc[4][4] = {};

    // prologue: stage tile 0 into buffer 0
    async16(apc0, lA);
    async16(apc1, lA + 4096);
    async16(bpc0, lB);
    async16(bpc1, lB + 4096);
    apc0 += 64; apc1 += 64; bpc0 += 64; bpc1 += 64;
    __syncthreads();   // vmcnt(0) drain: buffer 0 ready

    int bo_ = 0;   // byte offset of current buffer (0 or 8192)
    for (int tt = 0; tt < nt - 1; ++tt) {
        // prefetch next K-step into the other buffer (issue-early)
        const int po = bo_ ^ 8192;
        async16(apc0, lA + po);
        async16(apc1, lA + po + 4096);
        async16(bpc0, lB + po);
        async16(bpc1, lB + po + 4096);
        apc0 += 64; apc1 += 64; bpc0 += 64; bpc1 += 64;
        // compute current buffer: loads fly under ds_read + 16 MFMA
        gemm_compute((const ushort_t*)((const char*)As + bo_),
                     (const ushort_t*)((const char*)Bs + bo_),
                     wm, wn, l16, quad, acc);
        __syncthreads();   // single barrier/iter; drains prefetch after compute
        bo_ = po;
    }
    // final K-step: no prefetch
    gemm_compute((const ushort_t*)((const char*)As + bo_),
                 (const ushort_t*)((const char*)Bs + bo_),
                 wm, wn, l16, quad, acc);

    // epilogue: within 16x16 tile, row = quad*4+g, col = l16
    #pragma unroll
    for (int i = 0; i < 4; i++) {
        const int r0 = tileM + wm * 64 + i * 16 + quad * 4;
        #pragma unroll
        for (int j = 0; j < 4; j++) {
            const int c = tileN + wn * 64 + j * 16 + l16;
            float bv = 0.f;
            if (EPI == EPI_QKV) {
                const float* bp = bias;
                int cc = c;
                if (c >= 2560) { cc = c - 2560; bp = bias3; }
                else if (c >= 1280) { cc = c - 1280; bp = bias2; }
                bv = bp[cc];
            } else if (EPI == EPI_RELU) {
                bv = bias[c];
            } else if (EPI == EPI_RESID) {
                bv = (z == 0) ? bias[c] : 0.f;
            }
            #pragma unroll
            for (int g = 0; g < 4; g++) {
                const int r = r0 + g;
                const float v = acc[i][j][g] + bv;
                if (EPI == EPI_QKV) {
                    int cc = c;
                    ushort_t* ob = outB;
                    bool isV = false;
                    if (c >= 2560) { cc = c - 2560; ob = outB3; isV = true; }
                    else if (c >= 1280) { cc = c - 1280; ob = outB2; }
                    const int b = r >> 10, s = r & 1023;
                    const int h = cc / 80, d = cc - h * 80;
                    if (isV) ob[((size_t)((b * 16 + h) * 96 + d)) * 1024 + s] = f2bf(v);
                    else     ob[((size_t)((b * 16 + h) * 1024 + s)) * 96 + d] = f2bf(v);
                } else if (EPI == EPI_RELU) {
                    outB[(size_t)r * ldc + c] = f2bf(fmaxf(v, 0.f));
                } else if (EPI == EPI_RESID) {
                    atomicAdd(outF + (size_t)r * ldc + c, v);
                } else if (EPI == EPI_SC) {
                    float sv = acc[i][j][g] * scaleP;
                    if (c > r) sv -= 10000.f;
                    outF[z * cStr + (size_t)r * ldc + c] = sv;
                } else {  // EPI_CTX
                    if (c < 80) {
                        const int gg = g0 + (int)z;
                        const int b = gg >> 4, h = gg & 15;
                        outB[((size_t)(b * 1024 + r)) * 1280 + h * 80 + c] = f2bf(acc[i][j][g]);
                    }
                }
            }
        }
    }
}

// ---------------------------------------------------------------------------
// Host orchestration
// ---------------------------------------------------------------------------
extern "C" void kernel_launch(void* const* d_in, const int* in_sizes, int n_in,
                              void* d_out, int out_size, void* d_ws, size_t ws_size,
                              hipStream_t stream) {
    const int* ids = (const int*)d_in[0];
    const float* emb = (const float*)d_in[1];
    const float* Wq = (const float*)d_in[2];
    const float* Wk = (const float*)d_in[3];
    const float* Wv = (const float*)d_in[4];
    const float* Wo = (const float*)d_in[5];
    const float* bq = (const float*)d_in[6];
    const float* bk = (const float*)d_in[7];
    const float* bv = (const float*)d_in[8];
    const float* bo = (const float*)d_in[9];
    const float* W1 = (const float*)d_in[10];
    const float* b1 = (const float*)d_in[11];
    const float* W2 = (const float*)d_in[12];
    const float* b2 = (const float*)d_in[13];
    const float* ln1g = (const float*)d_in[14];
    const float* ln1b = (const float*)d_in[15];
    const float* ln2g = (const float*)d_in[16];
    const float* ln2b = (const float*)d_in[17];
    const float* lnfg = (const float*)d_in[18];
    const float* lnfb = (const float*)d_in[19];
    (void)in_sizes; (void)n_in; (void)out_size; (void)ws_size;

    char* p = (char*)d_ws;
    float* xf = (float*)p;          p += (size_t)2048 * 1280 * 4;     // residual (10.49 MB)
    ushort_t* nbuf = (ushort_t*)p;  p += (size_t)2048 * 1280 * 2;     // LN out bf16 (5.24 MB)
    ushort_t* qp = (ushort_t*)p;    p += (size_t)32 * 1024 * 96 * 2;  // q [bh][s][96] (6.29 MB)
    ushort_t* kp = (ushort_t*)p;    p += (size_t)32 * 1024 * 96 * 2;  // k [bh][s][96]
    ushort_t* vT = (ushort_t*)p;    p += (size_t)32 * 96 * 1024 * 2;  // v^T [bh][96][1024]
    ushort_t* ctx = (ushort_t*)p;   p += (size_t)2048 * 1280 * 2;     // attn out (5.24 MB)
    ushort_t* h1 = (ushort_t*)p;    p += (size_t)2048 * 8192 * 2;     // FFN hidden (33.55 MB)
    ushort_t* WT = (ushort_t*)p;    p += (size_t)8192 * 1280 * 2;     // bf16 W^T (20.97 MB)
    // attention score/prob buffers OVERLAP h1 (dead during attention) + WT:
    // Sb = CH*4 MB fp32, Pb = CH*2 MB bf16, CH=8 -> 32 MB + 16 MB
    float* Sb = (float*)h1;
    ushort_t* Pb = WT;
    const int CH = 8;

    const float scaleP = 0.11180339887498948f;   // 1/sqrt(80)

    embed_k<<<2048, 256, 0, stream>>>(ids, emb, xf);
    zero_k<<<4608, 256, 0, stream>>>((float4*)qp);   // qp,kp,vT = 18.87 MB contiguous

    for (int l = 0; l < 4; l++) {
        const float* Wq_l = Wq + (size_t)l * 1638400;
        const float* Wk_l = Wk + (size_t)l * 1638400;
        const float* Wv_l = Wv + (size_t)l * 1638400;
        const float* Wo_l = Wo + (size_t)l * 1638400;
        const float* W1_l = W1 + (size_t)l * 10485760;
        const float* W2_l = W2 + (size_t)l * 10485760;

        layernorm_k<ushort_t><<<2048, 256, 0, stream>>>(xf, ln1g + l * 1280, ln1b + l * 1280, nbuf);

        // WT rows 0..1279 = Wq^T, 1280..2559 = Wk^T, 2560..3839 = Wv^T
        convtrans_k<<<dim3(20, 20), 256, 0, stream>>>(Wq_l, WT, 1280, 1280);
        convtrans_k<<<dim3(20, 20), 256, 0, stream>>>(Wk_l, WT + (size_t)1280 * 1280, 1280, 1280);
        convtrans_k<<<dim3(20, 20), 256, 0, stream>>>(Wv_l, WT + (size_t)2560 * 1280, 1280, 1280);
        gemm_bt<EPI_QKV><<<dim3(30, 16, 1), 256, 0, stream>>>(
            nbuf, WT, bq + l * 1280, bk + l * 1280, bv + l * 1280,
            nullptr, qp, kp, vT, 1280, 1280, 1280, 3840, 0, 0, 0, 0, 0, 0.f);

        for (int c0 = 0; c0 < 32; c0 += CH) {
            gemm_bt<EPI_SC><<<dim3(8, 8, CH), 256, 0, stream>>>(
                qp + (size_t)c0 * 98304, kp + (size_t)c0 * 98304, nullptr, nullptr, nullptr,
                Sb, nullptr, nullptr, nullptr,
                96, 96, 96, 1024, 1024, 98304, 98304, 1048576, 0, scaleP);
            softmax_k<<<CH * 1024, 256, 0, stream>>>(Sb, Pb);
            gemm_bt<EPI_CTX><<<dim3(1, 8, CH), 256, 0, stream>>>(
                Pb, vT + (size_t)c0 * 98304, nullptr, nullptr, nullptr,
                nullptr, ctx, nullptr, nullptr,
                1024, 1024, 1024, 96, 0, 1048576, 98304, 0, c0, 0.f);
        }

        convtrans_k<<<dim3(20, 20), 256, 0, stream>>>(Wo_l, WT, 1280, 1280);
        // Wo projection: split-K x4 -> 640 blocks
        gemm_bt<EPI_RESID><<<dim3(10, 16, 4), 256, 0, stream>>>(
            ctx, WT, bo + l * 1280, nullptr, nullptr,
            xf, nullptr, nullptr, nullptr,
            1280, 1280, 1280, 1280, 1280, 0, 0, 0, 0, 0.f);

        layernorm_k<ushort_t><<<2048, 256, 0, stream>>>(xf, ln2g + l * 1280, ln2b + l * 1280, nbuf);

        convtrans_k<<<dim3(128, 20), 256, 0, stream>>>(W1_l, WT, 1280, 8192);
        gemm_bt<EPI_RELU><<<dim3(64, 16, 1), 256, 0, stream>>>(
            nbuf, WT, b1 + l * 8192, nullptr, nullptr,
            nullptr, h1, nullptr, nullptr,
            1280, 1280, 1280, 8192, 8192, 0, 0, 0, 0, 0.f);

        convtrans_k<<<dim3(20, 128), 256, 0, stream>>>(W2_l, WT, 8192, 1280);
        // FFN2: split-K x8 -> 1280 blocks, 32 K-iters per block
        gemm_bt<EPI_RESID><<<dim3(10, 16, 8), 256, 0, stream>>>(
            h1, WT, b2 + l * 1280, nullptr, nullptr,
            xf, nullptr, nullptr, nullptr,
            8192, 8192, 8192, 1280, 1280, 0, 0, 0, 0, 0.f);
    }

    layernorm_k<float><<<2048, 256, 0, stream>>>(xf, lnfg, lnfb, (float*)d_out);
}